// Round 8
// baseline (455.812 us; speedup 1.0000x reference)
//
#include <hip/hip_runtime.h>

typedef short v8s __attribute__((ext_vector_type(8)));
typedef float v4f __attribute__((ext_vector_type(4)));
typedef unsigned short v4us __attribute__((ext_vector_type(4)));

__device__ __forceinline__ unsigned short f2bf(float x) {
  union { float f; unsigned int u; } c; c.f = x;
  unsigned int u = c.u;
  return (unsigned short)((u + 0x7fffu + ((u >> 16) & 1u)) >> 16);
}
__device__ __forceinline__ float bf2f(unsigned int hi16) {
  union { unsigned int u; float f; } c; c.u = hi16 << 16;
  return c.f;
}
__device__ __forceinline__ ushort2 pk(float2 v) {
  ushort2 p; p.x = f2bf(v.x); p.y = f2bf(v.y); return p;
}

// Fold BN scale/shift AND the lin_l bias:  out = relu(z*s + t'), t' = (b - rm)*s + be.
// Also zeroes the gather sentinel row N of bufA (P1l) and bufB (P2l).
__global__ void bn_fold_k(const float* __restrict__ g1, const float* __restrict__ be1,
                          const float* __restrict__ rm1, const float* __restrict__ rv1,
                          const float* __restrict__ b1,
                          const float* __restrict__ g2, const float* __restrict__ be2,
                          const float* __restrict__ rm2, const float* __restrict__ rv2,
                          const float* __restrict__ b2,
                          float* __restrict__ s1, float* __restrict__ t1,
                          float* __restrict__ s2, float* __restrict__ t2,
                          unsigned short* __restrict__ bufA,
                          unsigned short* __restrict__ bufB, int N) {
  int i = threadIdx.x;
  if (i < 128) {
    float sv = g1[i] * rsqrtf(rv1[i] + 1e-5f);
    s1[i] = sv; t1[i] = (b1[i] - rm1[i]) * sv + be1[i];
    float sw = g2[i] * rsqrtf(rv2[i] + 1e-5f);
    s2[i] = sw; t2[i] = (b2[i] - rm2[i]) * sw + be2[i];
  }
  if (i < 64) {
    ((unsigned int*)(bufA + (long)N * 128))[i] = 0u;
    ((unsigned int*)(bufB + (long)N * 128))[i] = 0u;
  }
}

// Pack one 128-col weight into MFMA A-operand fragments:
// wpk[kc*4096 + n*32 + kk], n in [0,128). k >= K rows are ZERO (K-pad relies on this).
template<int K, int KC>
__global__ void pack1_k(const float* __restrict__ W, unsigned short* __restrict__ wpk) {
  int i = blockIdx.x * 256 + threadIdx.x;
  if (i >= KC * 4096) return;
  int kk = i & 31, n = (i >> 5) & 127, kc = i >> 12;
  int k = kc * 32 + kk;
  wpk[i] = (k < K) ? f2bf(W[k * 128 + n]) : (unsigned short)0;
}

// ---------- CSR build ----------
__global__ void zero_i_k(int* __restrict__ p, int n) {
  int i = blockIdx.x * 256 + threadIdx.x;
  if (i < n) p[i] = 0;
}
__global__ void count_k(const int* __restrict__ dst, int* __restrict__ degi, int E) {
  int i = blockIdx.x * 256 + threadIdx.x;
  if (i < E) atomicAdd(&degi[dst[i]], 1);
}
__global__ __launch_bounds__(256) void scan1_k(const int* __restrict__ degi,
                                               int* __restrict__ rowptr,
                                               int* __restrict__ bsum, int N) {
  __shared__ int sd[256];
  const int t = threadIdx.x;
  const int base = blockIdx.x * 1024 + t * 4;
  int v[4];
#pragma unroll
  for (int j = 0; j < 4; ++j) v[j] = (base + j < N) ? degi[base + j] : 0;
  const int tot = v[0] + v[1] + v[2] + v[3];
  sd[t] = tot;
  __syncthreads();
  for (int off = 1; off < 256; off <<= 1) {
    int o = (t >= off) ? sd[t - off] : 0;
    __syncthreads();
    sd[t] += o;
    __syncthreads();
  }
  int e = sd[t] - tot;
#pragma unroll
  for (int j = 0; j < 4; ++j) {
    if (base + j < N) rowptr[base + j] = e;
    e += v[j];
  }
  if (t == 255) bsum[blockIdx.x] = sd[255];
}
__global__ __launch_bounds__(256) void scan2_k(int* __restrict__ bsum, int nb) {
  __shared__ int sd[256];
  const int t = threadIdx.x;
  const int v = (t < nb) ? bsum[t] : 0;
  sd[t] = v;
  __syncthreads();
  for (int off = 1; off < 256; off <<= 1) {
    int o = (t >= off) ? sd[t - off] : 0;
    __syncthreads();
    sd[t] += o;
    __syncthreads();
  }
  if (t < nb) bsum[t] = sd[t] - v;
}
__global__ void scan3_k(int* __restrict__ rowptr, int* __restrict__ cursor,
                        const int* __restrict__ bsum, int N, int E) {
  int i = blockIdx.x * 256 + threadIdx.x;
  if (i < N) {
    int v = rowptr[i] + bsum[i >> 10];
    rowptr[i] = v;
    cursor[i] = v;
  } else if (i == N) {
    rowptr[N] = E;
  }
}
__global__ void fill_k(const int* __restrict__ src, const int* __restrict__ dst,
                       int* __restrict__ cursor, int* __restrict__ nbr, int E) {
  int i = blockIdx.x * 256 + threadIdx.x;
  if (i < E) {
    int p = atomicAdd(&cursor[dst[i]], 1);
    nbr[p] = src[i];
  }
}

// ---------- dense GEMM (layer 1 only): P1l = x @ W1l ----------
// Linear-coalesced fp32 staging into LDS (bf16-convert, K padded 130->160),
// swapped MFMA operands (A-op = weights, B-op = nodes), 8-B coalesced stores.
template<int KC>
__global__ __launch_bounds__(256) void gemmL_k(const float* __restrict__ Asrc,
                                               const unsigned short* __restrict__ wpk,
                                               unsigned short* __restrict__ O, int N) {
  constexpr int KP = KC * 32;
  constexpr int LDA = KP + 8;
  __shared__ __align__(16) unsigned short a_s[64][LDA];
  const int tid = threadIdx.x;
  const int node0 = blockIdx.x * 64;

  {  // zero pad cols [130,136) and [136,168): disjoint from data cols [0,130)
    const int zr = tid >> 2, zq = tid & 3;
    v8s z = {0, 0, 0, 0, 0, 0, 0, 0};
    *(v8s*)&a_s[zr][136 + zq * 8] = z;
    if (tid < 192) {
      const int r3 = tid / 3, p3 = tid - 3 * r3;
      *(unsigned int*)&a_s[r3][130 + 2 * p3] = 0u;
    }
  }
  const float* xb = Asrc + (long)node0 * 130;
  if (node0 + 64 <= N) {      // full tile: unguarded linear float4 sweep
    float4 v[9];
#pragma unroll
    for (int i = 0; i < 9; ++i) {
      const int g = i * 256 + tid;
      if (g < 2080) v[i] = *(const float4*)(xb + 4 * g);
    }
#pragma unroll
    for (int i = 0; i < 9; ++i) {
      const int g = i * 256 + tid;
      if (g < 2080) {
        const int p0 = 2 * g, p1 = 2 * g + 1;
        const int r0_ = (p0 * 4033) >> 18, r1_ = (p1 * 4033) >> 18;
        const int c0_ = p0 - 65 * r0_, c1_ = p1 - 65 * r1_;
        *(ushort2*)&a_s[r0_][2 * c0_] = pk(make_float2(v[i].x, v[i].y));
        *(ushort2*)&a_s[r1_][2 * c1_] = pk(make_float2(v[i].z, v[i].w));
      }
    }
  } else {                    // partial tail tile: per-pair guarded float2
    for (int i = 0; i < 9; ++i) {
      const int g = i * 256 + tid;
      if (g < 2080) {
#pragma unroll
        for (int h = 0; h < 2; ++h) {
          const int p = 2 * g + h;
          const int r = (p * 4033) >> 18;
          const int c = p - 65 * r;
          float2 vv = make_float2(0.f, 0.f);
          if (node0 + r < N)
            vv = *(const float2*)(Asrc + (long)(node0 + r) * 130 + 2 * c);
          *(ushort2*)&a_s[r][2 * c] = pk(vv);
        }
      }
    }
  }
  __syncthreads();

  const int wave = tid >> 6, lane = tid & 63;
  const int quad = lane >> 4, l16 = lane & 15;
  v4f acc[4][2];
#pragma unroll
  for (int mt = 0; mt < 4; ++mt)
#pragma unroll
    for (int nt = 0; nt < 2; ++nt) acc[mt][nt] = (v4f){0.f, 0.f, 0.f, 0.f};

  const unsigned short* wb = wpk + (wave * 32 + l16) * 32 + quad * 8;
#pragma unroll
  for (int kc = 0; kc < KC; ++kc) {
    v8s wf[2];
#pragma unroll
    for (int nt = 0; nt < 2; ++nt)
      wf[nt] = *(const v8s*)(wb + kc * 4096 + nt * 512);
#pragma unroll
    for (int mt = 0; mt < 4; ++mt) {
      v8s nf = *(const v8s*)(&a_s[mt * 16 + l16][kc * 32 + quad * 8]);
#pragma unroll
      for (int nt = 0; nt < 2; ++nt)
        acc[mt][nt] = __builtin_amdgcn_mfma_f32_16x16x32_bf16(wf[nt], nf, acc[mt][nt], 0, 0, 0);
    }
  }

#pragma unroll
  for (int mt = 0; mt < 4; ++mt) {
    const int rw = node0 + mt * 16 + l16;
    if (rw < N) {
#pragma unroll
      for (int nt = 0; nt < 2; ++nt) {
        const int oc = wave * 32 + nt * 16 + quad * 4;
        v4us v;
        v[0] = f2bf(acc[mt][nt][0]);
        v[1] = f2bf(acc[mt][nt][1]);
        v[2] = f2bf(acc[mt][nt][2]);
        v[3] = f2bf(acc[mt][nt][3]);
        *(v4us*)(O + (long)rw * 128 + oc) = v;
      }
    }
  }
}

// ---------- FUSED layer-1 aggregate + layer-2 dense GEMM ----------
//   h1 = relu((mean(P1l[nbr]) + x_tile @ W1r) * s1 + t1)   [kept in LDS only]
//   P2l = h1 @ W2l ; P2r = h1 @ W2r                        [written to global]
// 16 nodes/block, scalarized gather control path (wave-uniform CSR state).
// h1 never touches HBM; gemmL-L2 is eliminated.
template<int KC>   // KC=5 (x fp32 source, K 130->160)
__global__ __launch_bounds__(256) void spmmF_k(const unsigned short* __restrict__ gsrc,
                                               const float* __restrict__ xsrc,
                                               const unsigned short* __restrict__ wpkr,
                                               const unsigned short* __restrict__ w2l,
                                               const unsigned short* __restrict__ w2r,
                                               const int* __restrict__ rowptr,
                                               const int* __restrict__ nbr,
                                               const float* __restrict__ sc,
                                               const float* __restrict__ tc,
                                               unsigned short* __restrict__ P2l,
                                               unsigned short* __restrict__ P2r,
                                               int N, int E) {
  __shared__ __align__(16) unsigned short xls[16][168];
  __shared__ __align__(16) float rls[16][132];
  __shared__ __align__(16) unsigned short h1s[16][136];
  const int tid = threadIdx.x;
  const int lane = tid & 63;
  const int wu = __builtin_amdgcn_readfirstlane(tid >> 6);   // uniform wave id
  const int quad = lane >> 4, l16 = lane & 15;
  const int nb0 = blockIdx.x * 16;

  // ---- stage the block's 16 x rows into xls (bf16) ----
  {  // zero pad cols [130,136) and [136,168)
    if (tid < 64) {
      v8s z = {0, 0, 0, 0, 0, 0, 0, 0};
      *(v8s*)&xls[tid >> 2][136 + (tid & 3) * 8] = z;
    }
    if (tid < 48) {
      const int r3 = tid / 3, p3 = tid - 3 * r3;
      *(unsigned int*)&xls[r3][130 + 2 * p3] = 0u;
    }
  }
  const float* xb = xsrc + (long)nb0 * 130;
  if (nb0 + 16 <= N) {   // full tile: linear float4 sweep (520 float4s)
    float4 v[3];
#pragma unroll
    for (int i = 0; i < 3; ++i) {
      const int g = i * 256 + tid;
      if (g < 520) v[i] = *(const float4*)(xb + 4 * g);
    }
#pragma unroll
    for (int i = 0; i < 3; ++i) {
      const int g = i * 256 + tid;
      if (g < 520) {
        const int p0 = 2 * g, p1 = 2 * g + 1;
        const int r0_ = (p0 * 4033) >> 18, r1_ = (p1 * 4033) >> 18;
        const int c0_ = p0 - 65 * r0_, c1_ = p1 - 65 * r1_;
        *(ushort2*)&xls[r0_][2 * c0_] = pk(make_float2(v[i].x, v[i].y));
        *(ushort2*)&xls[r1_][2 * c1_] = pk(make_float2(v[i].z, v[i].w));
      }
    }
  } else {               // tail: per-pair guarded
    for (int i = 0; i < 3; ++i) {
      const int g = i * 256 + tid;
      if (g < 520) {
#pragma unroll
        for (int h = 0; h < 2; ++h) {
          const int p = 2 * g + h;
          const int r = (p * 4033) >> 18;
          const int c = p - 65 * r;
          float2 vv = make_float2(0.f, 0.f);
          if (nb0 + r < N)
            vv = *(const float2*)(xsrc + (long)(nb0 + r) * 130 + 2 * c);
          *(ushort2*)&xls[r][2 * c] = pk(vv);
        }
      }
    }
  }

  // ---- scalar CSR setup (all wave-uniform -> SALU/s_load) ----
  const int nb = nb0 + wu * 4;
  int r0[4], d[4];
#pragma unroll
  for (int r = 0; r < 4; ++r) {
    const int i0 = min(nb + r, N);
    const int i1 = min(nb + r + 1, N);
    r0[r] = rowptr[i0];
    const int r1 = rowptr[i1];
    d[r] = (nb + r < N) ? (r1 - r0[r]) : 0;
  }
  const int dm = max(max(d[0], d[1]), max(d[2], d[3]));
  float2 a[4];
#pragma unroll
  for (int r = 0; r < 4; ++r) a[r] = make_float2(0.f, 0.f);

  __syncthreads();   // xls ready

  // ---- root GEMM: 16 nodes x 128 feats; wave wu covers feats [wu*32, wu*32+32) ----
  {
    v4f racc[2];
    racc[0] = (v4f){0.f, 0.f, 0.f, 0.f};
    racc[1] = (v4f){0.f, 0.f, 0.f, 0.f};
    const unsigned short* wb = wpkr + (wu * 32 + l16) * 32 + quad * 8;
#pragma unroll
    for (int kc = 0; kc < KC; ++kc) {
      v8s nf = *(const v8s*)&xls[l16][kc * 32 + quad * 8];
#pragma unroll
      for (int nt = 0; nt < 2; ++nt) {
        v8s wf = *(const v8s*)(wb + kc * 4096 + nt * 512);
        racc[nt] = __builtin_amdgcn_mfma_f32_16x16x32_bf16(wf, nf, racc[nt], 0, 0, 0);
      }
    }
#pragma unroll
    for (int nt = 0; nt < 2; ++nt)
      *(v4f*)&rls[l16][wu * 32 + nt * 16 + quad * 4] = racc[nt];
  }

  // ---- gather-mean: uniform chunk loop, scalar addresses ----
  const int lofs = lane << 1;
  for (int e0 = 0; e0 < dm; e0 += 8) {
    unsigned int u[4][8];
#pragma unroll
    for (int j = 0; j < 8; ++j)
#pragma unroll
      for (int r = 0; r < 4; ++r) {
        const int e = e0 + j;
        const int nv = nbr[min(r0[r] + e, E - 1)];        // uniform s_load (clamped)
        const int idx = (e < d[r]) ? nv : N;              // uniform s_cselect
        u[r][j] = *(const unsigned int*)(gsrc + ((long)idx << 7) + lofs);
      }
#pragma unroll
    for (int r = 0; r < 4; ++r)
#pragma unroll
      for (int j = 0; j < 8; ++j) {
        a[r].x += bf2f(u[r][j] & 0xffffu);
        a[r].y += bf2f(u[r][j] >> 16);
      }
  }

  __syncthreads();   // rls ready

  // ---- h1 = relu((mean + root)*s1 + t1') -> bf16 into h1s (LDS only) ----
  {
    const float2 sv = *(const float2*)(sc + 2 * lane);
    const float2 tv = *(const float2*)(tc + 2 * lane);
#pragma unroll
    for (int r = 0; r < 4; ++r) {
      const float inv = 1.0f / fmaxf((float)d[r], 1.0f);
      const float2 rt = *(const float2*)&rls[wu * 4 + r][2 * lane];
      float yx = fmaxf((a[r].x * inv + rt.x) * sv.x + tv.x, 0.f);
      float yy = fmaxf((a[r].y * inv + rt.y) * sv.y + tv.y, 0.f);
      *(ushort2*)&h1s[wu * 4 + r][2 * lane] = pk(make_float2(yx, yy));
    }
  }

  __syncthreads();   // h1s ready

  // ---- layer-2 GEMM: 16 nodes x 256 cols; wave wu covers cols [wu*64, wu*64+64) ----
  // waves 0,1 -> P2l cols 0..127; waves 2,3 -> P2r cols 0..127.
  {
    unsigned short* ob = (wu < 2) ? P2l : P2r;
    const unsigned short* w2 = (wu < 2) ? w2l : w2r;
    const int cb = (wu & 1) * 64;
    v4f acc[4];
#pragma unroll
    for (int nt = 0; nt < 4; ++nt) acc[nt] = (v4f){0.f, 0.f, 0.f, 0.f};
    const unsigned short* wb2 = w2 + (cb + l16) * 32 + quad * 8;
#pragma unroll
    for (int kc = 0; kc < 4; ++kc) {
      v8s nf = *(const v8s*)&h1s[l16][kc * 32 + quad * 8];
#pragma unroll
      for (int nt = 0; nt < 4; ++nt) {
        v8s wf = *(const v8s*)(wb2 + kc * 4096 + nt * 512);
        acc[nt] = __builtin_amdgcn_mfma_f32_16x16x32_bf16(wf, nf, acc[nt], 0, 0, 0);
      }
    }
    const int rw = nb0 + l16;
    if (rw < N) {
#pragma unroll
      for (int nt = 0; nt < 4; ++nt) {
        const int oc = cb + nt * 16 + quad * 4;
        v4us v;
        v[0] = f2bf(acc[nt][0]);
        v[1] = f2bf(acc[nt][1]);
        v[2] = f2bf(acc[nt][2]);
        v[3] = f2bf(acc[nt][3]);
        *(v4us*)(ob + (long)rw * 128 + oc) = v;
      }
    }
  }
}

// ---------- light layer-2 aggregate: out = relu((mean(P2l[nbr]) + P2r[node])*s2 + t2')
// No LDS, no MFMA: gather + contiguous root read + epilogue. Scalarized control path.
__global__ __launch_bounds__(256) void spmmL_k(const unsigned short* __restrict__ gsrc,
                                               const unsigned short* __restrict__ rsrc,
                                               const int* __restrict__ rowptr,
                                               const int* __restrict__ nbr,
                                               const float* __restrict__ sc,
                                               const float* __restrict__ tc,
                                               float* __restrict__ out, int N, int E) {
  const int tid = threadIdx.x;
  const int lane = tid & 63;
  const int wu = __builtin_amdgcn_readfirstlane(tid >> 6);
  const int nb = blockIdx.x * 16 + wu * 4;

  int r0[4], d[4];
#pragma unroll
  for (int r = 0; r < 4; ++r) {
    const int i0 = min(nb + r, N);
    const int i1 = min(nb + r + 1, N);
    r0[r] = rowptr[i0];
    const int r1 = rowptr[i1];
    d[r] = (nb + r < N) ? (r1 - r0[r]) : 0;
  }
  const int dm = max(max(d[0], d[1]), max(d[2], d[3]));
  float2 a[4];
#pragma unroll
  for (int r = 0; r < 4; ++r) a[r] = make_float2(0.f, 0.f);

  const int lofs = lane << 1;
  for (int e0 = 0; e0 < dm; e0 += 8) {
    unsigned int u[4][8];
#pragma unroll
    for (int j = 0; j < 8; ++j)
#pragma unroll
      for (int r = 0; r < 4; ++r) {
        const int e = e0 + j;
        const int nv = nbr[min(r0[r] + e, E - 1)];
        const int idx = (e < d[r]) ? nv : N;
        u[r][j] = *(const unsigned int*)(gsrc + ((long)idx << 7) + lofs);
      }
#pragma unroll
    for (int r = 0; r < 4; ++r)
#pragma unroll
      for (int j = 0; j < 8; ++j) {
        a[r].x += bf2f(u[r][j] & 0xffffu);
        a[r].y += bf2f(u[r][j] >> 16);
      }
  }

  const float2 sv = *(const float2*)(sc + 2 * lane);
  const float2 tv = *(const float2*)(tc + 2 * lane);
#pragma unroll
  for (int r = 0; r < 4; ++r) {
    if (nb + r < N) {
      const float inv = 1.0f / fmaxf((float)d[r], 1.0f);
      const unsigned int ur = *(const unsigned int*)(rsrc + ((long)(nb + r) << 7) + lofs);
      float yx = fmaxf((a[r].x * inv + bf2f(ur & 0xffffu)) * sv.x + tv.x, 0.f);
      float yy = fmaxf((a[r].y * inv + bf2f(ur >> 16)) * sv.y + tv.y, 0.f);
      *(float2*)(out + (long)(nb + r) * 128 + 2 * lane) = make_float2(yx, yy);
    }
  }
}

extern "C" void kernel_launch(void* const* d_in, const int* in_sizes, int n_in,
                              void* d_out, int out_size, void* d_ws, size_t ws_size,
                              hipStream_t stream) {
  const float* x   = (const float*)d_in[0];
  const int*   ei  = (const int*)d_in[1];
  const float* W1l = (const float*)d_in[2];
  const float* b1  = (const float*)d_in[3];
  const float* W1r = (const float*)d_in[4];
  const float* g1  = (const float*)d_in[5];
  const float* be1 = (const float*)d_in[6];
  const float* rm1 = (const float*)d_in[7];
  const float* rv1 = (const float*)d_in[8];
  const float* W2l = (const float*)d_in[9];
  const float* b2  = (const float*)d_in[10];
  const float* W2r = (const float*)d_in[11];
  const float* g2  = (const float*)d_in[12];
  const float* be2 = (const float*)d_in[13];
  const float* rm2 = (const float*)d_in[14];
  const float* rv2 = (const float*)d_in[15];

  const int E = in_sizes[1] / 2;
  const int N = in_sizes[0] / 130;
  const int* src = ei;
  const int* dst = ei + E;

  // workspace carve (~158 MB)
  unsigned short* bufA = (unsigned short*)d_ws;            // P1l ((N+1)*128, sentinel)
  unsigned short* bufB = bufA + (size_t)(N + 1) * 128;     // P2l ((N+1)*128, sentinel)
  unsigned short* bufC = bufB + (size_t)(N + 1) * 128;     // P2r (N*128)
  unsigned short* wp1l = bufC + (size_t)N * 128;           // 5*4096
  unsigned short* wp1r = wp1l + 5 * 4096;                  // 5*4096
  unsigned short* wp2l = wp1r + 5 * 4096;                  // 4*4096
  unsigned short* wp2r = wp2l + 4 * 4096;                  // 4*4096
  float* s1 = (float*)(wp2r + 4 * 4096);
  float* t1 = s1 + 128;
  float* s2 = t1 + 128;
  float* t2 = s2 + 128;
  int* degi   = (int*)(t2 + 128);   // N (reused as cursor)
  int* rowptr = degi + N;           // N+1
  int* bsum   = rowptr + N + 1;     // 256
  int* nbr    = bsum + 256;         // E

  hipLaunchKernelGGL(bn_fold_k, dim3(1), dim3(128), 0, stream,
                     g1, be1, rm1, rv1, b1, g2, be2, rm2, rv2, b2,
                     s1, t1, s2, t2, bufA, bufB, N);
  hipLaunchKernelGGL((pack1_k<130, 5>), dim3(80), dim3(256), 0, stream, W1l, wp1l);
  hipLaunchKernelGGL((pack1_k<130, 5>), dim3(80), dim3(256), 0, stream, W1r, wp1r);
  hipLaunchKernelGGL((pack1_k<128, 4>), dim3(64), dim3(256), 0, stream, W2l, wp2l);
  hipLaunchKernelGGL((pack1_k<128, 4>), dim3(64), dim3(256), 0, stream, W2r, wp2r);

  // CSR build
  hipLaunchKernelGGL(zero_i_k, dim3((N + 255) / 256), dim3(256), 0, stream, degi, N);
  hipLaunchKernelGGL(count_k, dim3((E + 255) / 256), dim3(256), 0, stream, dst, degi, E);
  const int nb = (N + 1023) / 1024;
  hipLaunchKernelGGL(scan1_k, dim3(nb), dim3(256), 0, stream, degi, rowptr, bsum, N);
  hipLaunchKernelGGL(scan2_k, dim3(1), dim3(256), 0, stream, bsum, nb);
  hipLaunchKernelGGL(scan3_k, dim3((N + 256) / 256), dim3(256), 0, stream,
                     rowptr, degi, bsum, N, E);
  hipLaunchKernelGGL(fill_k, dim3((E + 255) / 256), dim3(256), 0, stream,
                     src, dst, degi, nbr, E);

  const int ngb = (N + 63) / 64;
  const int nsb = (N + 15) / 16;

  // layer 1 dense: P1l = x @ W1l
  hipLaunchKernelGGL((gemmL_k<5>), dim3(ngb), dim3(256), 0, stream, x, wp1l, bufA, N);
  // fused: h1 (LDS) = relu((mean(P1l[nbr]) + x@W1r)*s1+t1'); P2l = h1@W2l; P2r = h1@W2r
  hipLaunchKernelGGL((spmmF_k<5>), dim3(nsb), dim3(256), 0, stream,
                     bufA, x, wp1r, wp2l, wp2r, rowptr, nbr, s1, t1,
                     bufB, bufC, N, E);
  // light layer-2 aggregate -> d_out fp32
  hipLaunchKernelGGL(spmmL_k, dim3(nsb), dim3(256), 0, stream,
                     bufB, bufC, rowptr, nbr, s2, t2, (float*)d_out, N, E);
}

// Round 9
// 416.739 us; speedup vs baseline: 1.0938x; 1.0938x over previous
//
#include <hip/hip_runtime.h>

typedef short v8s __attribute__((ext_vector_type(8)));
typedef float v4f __attribute__((ext_vector_type(4)));
typedef unsigned short v4us __attribute__((ext_vector_type(4)));

__device__ __forceinline__ unsigned short f2bf(float x) {
  union { float f; unsigned int u; } c; c.f = x;
  unsigned int u = c.u;
  return (unsigned short)((u + 0x7fffu + ((u >> 16) & 1u)) >> 16);
}
__device__ __forceinline__ float bf2f(unsigned int hi16) {
  union { unsigned int u; float f; } c; c.u = hi16 << 16;
  return c.f;
}
__device__ __forceinline__ ushort2 pk(float2 v) {
  ushort2 p; p.x = f2bf(v.x); p.y = f2bf(v.y); return p;
}

// Pack one 128-col weight into MFMA A-operand fragments (runtime K/limit):
// wpk[kc*4096 + n*32 + kk], n in [0,128). k >= K entries are ZERO (K-pad relies on it).
__device__ __forceinline__ void pack_dev(const float* __restrict__ W,
                                         unsigned short* __restrict__ wpk,
                                         int K, int tot, int i) {
  if (i >= tot) return;
  const int kk = i & 31, n = (i >> 5) & 127, kc = i >> 12;
  const int k = kc * 32 + kk;
  wpk[i] = (k < K) ? f2bf(W[k * 128 + n]) : (unsigned short)0;
}

// ---------- ONE setup dispatch: zero degi | 4 weight packs | BN-fold | sentinel ----------
// All parts are mutually independent. Block-range dispatch:
//   [0, NZB)            : degi zero
//   [NZB, +80)          : pack W1l (K=130, 5*4096)
//   [+80, +160)         : pack W1r
//   [+160, +224)        : pack W2l (K=128, 4*4096)
//   [+224, +288)        : pack W2r
//   last block          : bn_fold (s/t fold incl. lin_l bias) + zero bufA sentinel row N
__global__ void setup_k(const float* __restrict__ g1, const float* __restrict__ be1,
                        const float* __restrict__ rm1, const float* __restrict__ rv1,
                        const float* __restrict__ b1,
                        const float* __restrict__ g2, const float* __restrict__ be2,
                        const float* __restrict__ rm2, const float* __restrict__ rv2,
                        const float* __restrict__ b2,
                        const float* __restrict__ W1l, const float* __restrict__ W1r,
                        const float* __restrict__ W2l, const float* __restrict__ W2r,
                        float* __restrict__ s1, float* __restrict__ t1,
                        float* __restrict__ s2, float* __restrict__ t2,
                        unsigned short* __restrict__ wp1l, unsigned short* __restrict__ wp1r,
                        unsigned short* __restrict__ wp2l, unsigned short* __restrict__ wp2r,
                        unsigned short* __restrict__ bufA, int* __restrict__ degi,
                        int N, int NZB) {
  const int b = blockIdx.x, tid = threadIdx.x;
  if (b < NZB) {
    const int i = b * 256 + tid;
    if (i < N) degi[i] = 0;
    return;
  }
  int r = b - NZB;
  if (r < 80)  { pack_dev(W1l, wp1l, 130, 5 * 4096, r * 256 + tid); return; }
  r -= 80;
  if (r < 80)  { pack_dev(W1r, wp1r, 130, 5 * 4096, r * 256 + tid); return; }
  r -= 80;
  if (r < 64)  { pack_dev(W2l, wp2l, 128, 4 * 4096, r * 256 + tid); return; }
  r -= 64;
  if (r < 64)  { pack_dev(W2r, wp2r, 128, 4 * 4096, r * 256 + tid); return; }
  // final block: BN fold + sentinel
  if (tid < 128) {
    float sv = g1[tid] * rsqrtf(rv1[tid] + 1e-5f);
    s1[tid] = sv; t1[tid] = (b1[tid] - rm1[tid]) * sv + be1[tid];
    float sw = g2[tid] * rsqrtf(rv2[tid] + 1e-5f);
    s2[tid] = sw; t2[tid] = (b2[tid] - rm2[tid]) * sw + be2[tid];
  }
  if (tid < 64) ((unsigned int*)(bufA + (long)N * 128))[tid] = 0u;
}

// ---------- CSR scan/fill (unchanged) ----------
__global__ __launch_bounds__(256) void scan1_k(const int* __restrict__ degi,
                                               int* __restrict__ rowptr,
                                               int* __restrict__ bsum, int N) {
  __shared__ int sd[256];
  const int t = threadIdx.x;
  const int base = blockIdx.x * 1024 + t * 4;
  int v[4];
#pragma unroll
  for (int j = 0; j < 4; ++j) v[j] = (base + j < N) ? degi[base + j] : 0;
  const int tot = v[0] + v[1] + v[2] + v[3];
  sd[t] = tot;
  __syncthreads();
  for (int off = 1; off < 256; off <<= 1) {
    int o = (t >= off) ? sd[t - off] : 0;
    __syncthreads();
    sd[t] += o;
    __syncthreads();
  }
  int e = sd[t] - tot;
#pragma unroll
  for (int j = 0; j < 4; ++j) {
    if (base + j < N) rowptr[base + j] = e;
    e += v[j];
  }
  if (t == 255) bsum[blockIdx.x] = sd[255];
}
__global__ __launch_bounds__(256) void scan2_k(int* __restrict__ bsum, int nb) {
  __shared__ int sd[256];
  const int t = threadIdx.x;
  const int v = (t < nb) ? bsum[t] : 0;
  sd[t] = v;
  __syncthreads();
  for (int off = 1; off < 256; off <<= 1) {
    int o = (t >= off) ? sd[t - off] : 0;
    __syncthreads();
    sd[t] += o;
    __syncthreads();
  }
  if (t < nb) bsum[t] = sd[t] - v;
}
__global__ void scan3_k(int* __restrict__ rowptr, int* __restrict__ cursor,
                        const int* __restrict__ bsum, int N, int E) {
  int i = blockIdx.x * 256 + threadIdx.x;
  if (i < N) {
    int v = rowptr[i] + bsum[i >> 10];
    rowptr[i] = v;
    cursor[i] = v;
  } else if (i == N) {
    rowptr[N] = E;
  }
}
__global__ void fill_k(const int* __restrict__ src, const int* __restrict__ dst,
                       int* __restrict__ cursor, int* __restrict__ nbr, int E) {
  int i = blockIdx.x * 256 + threadIdx.x;
  if (i < E) {
    int p = atomicAdd(&cursor[dst[i]], 1);
    nbr[p] = src[i];
  }
}

// ---------- FUSED dispatch: L1 dense GEMM (P1l = x @ W1l)  +  edge count ----------
// Blocks [0, ngb): round-4 GEMM structure (linear-coalesced fp32 staging -> LDS bf16,
// swapped MFMA operands, 8-B coalesced stores). Blocks [ngb, ...): count degi.
// The two parts share no data; the atomic-heavy count hides under the latency-bound GEMM.
__global__ __launch_bounds__(256) void gemmc_k(const float* __restrict__ Asrc,
                                               const unsigned short* __restrict__ wpk,
                                               unsigned short* __restrict__ O,
                                               const int* __restrict__ dst,
                                               int* __restrict__ degi,
                                               int N, int E, int ngb) {
  constexpr int KC = 5;
  constexpr int KP = KC * 32;
  constexpr int LDA = KP + 8;
  __shared__ __align__(16) unsigned short a_s[64][LDA];
  const int tid = threadIdx.x;

  if ((int)blockIdx.x >= ngb) {   // ---- edge-count part ----
    const int i = ((int)blockIdx.x - ngb) * 256 + tid;
    if (i < E) atomicAdd(&degi[dst[i]], 1);
    return;
  }

  const int node0 = blockIdx.x * 64;
  {  // zero pad cols [130,136) and [136,168): disjoint from data cols [0,130)
    const int zr = tid >> 2, zq = tid & 3;
    v8s z = {0, 0, 0, 0, 0, 0, 0, 0};
    *(v8s*)&a_s[zr][136 + zq * 8] = z;
    if (tid < 192) {
      const int r3 = tid / 3, p3 = tid - 3 * r3;
      *(unsigned int*)&a_s[r3][130 + 2 * p3] = 0u;
    }
  }
  const float* xb = Asrc + (long)node0 * 130;
  if (node0 + 64 <= N) {      // full tile: unguarded linear float4 sweep
    float4 v[9];
#pragma unroll
    for (int i = 0; i < 9; ++i) {
      const int g = i * 256 + tid;
      if (g < 2080) v[i] = *(const float4*)(xb + 4 * g);
    }
#pragma unroll
    for (int i = 0; i < 9; ++i) {
      const int g = i * 256 + tid;
      if (g < 2080) {
        const int p0 = 2 * g, p1 = 2 * g + 1;
        const int r0_ = (p0 * 4033) >> 18, r1_ = (p1 * 4033) >> 18;
        const int c0_ = p0 - 65 * r0_, c1_ = p1 - 65 * r1_;
        *(ushort2*)&a_s[r0_][2 * c0_] = pk(make_float2(v[i].x, v[i].y));
        *(ushort2*)&a_s[r1_][2 * c1_] = pk(make_float2(v[i].z, v[i].w));
      }
    }
  } else {                    // partial tail tile: per-pair guarded float2
    for (int i = 0; i < 9; ++i) {
      const int g = i * 256 + tid;
      if (g < 2080) {
#pragma unroll
        for (int h = 0; h < 2; ++h) {
          const int p = 2 * g + h;
          const int r = (p * 4033) >> 18;
          const int c = p - 65 * r;
          float2 vv = make_float2(0.f, 0.f);
          if (node0 + r < N)
            vv = *(const float2*)(Asrc + (long)(node0 + r) * 130 + 2 * c);
          *(ushort2*)&a_s[r][2 * c] = pk(vv);
        }
      }
    }
  }
  __syncthreads();

  const int wave = tid >> 6, lane = tid & 63;
  const int quad = lane >> 4, l16 = lane & 15;
  v4f acc[4][2];
#pragma unroll
  for (int mt = 0; mt < 4; ++mt)
#pragma unroll
    for (int nt = 0; nt < 2; ++nt) acc[mt][nt] = (v4f){0.f, 0.f, 0.f, 0.f};

  const unsigned short* wb = wpk + (wave * 32 + l16) * 32 + quad * 8;
#pragma unroll
  for (int kc = 0; kc < KC; ++kc) {
    v8s wf[2];
#pragma unroll
    for (int nt = 0; nt < 2; ++nt)
      wf[nt] = *(const v8s*)(wb + kc * 4096 + nt * 512);
#pragma unroll
    for (int mt = 0; mt < 4; ++mt) {
      v8s nf = *(const v8s*)(&a_s[mt * 16 + l16][kc * 32 + quad * 8]);
#pragma unroll
      for (int nt = 0; nt < 2; ++nt)
        acc[mt][nt] = __builtin_amdgcn_mfma_f32_16x16x32_bf16(wf[nt], nf, acc[mt][nt], 0, 0, 0);
    }
  }

#pragma unroll
  for (int mt = 0; mt < 4; ++mt) {
    const int rw = node0 + mt * 16 + l16;
    if (rw < N) {
#pragma unroll
      for (int nt = 0; nt < 2; ++nt) {
        const int oc = wave * 32 + nt * 16 + quad * 4;
        v4us v;
        v[0] = f2bf(acc[mt][nt][0]);
        v[1] = f2bf(acc[mt][nt][1]);
        v[2] = f2bf(acc[mt][nt][2]);
        v[3] = f2bf(acc[mt][nt][3]);
        *(v4us*)(O + (long)rw * 128 + oc) = v;
      }
    }
  }
}

// ---------- dense GEMM, bf16 source (layer 2): P2l = h1 @ W2l ----------
template<int KC>
__global__ __launch_bounds__(256) void gemmB_k(const unsigned short* __restrict__ Asrc,
                                               const unsigned short* __restrict__ wpk,
                                               unsigned short* __restrict__ O, int N) {
  constexpr int KP = KC * 32;
  constexpr int LDA = KP + 8;
  __shared__ __align__(16) unsigned short a_s[64][LDA];
  const int tid = threadIdx.x;
  const int node0 = blockIdx.x * 64;

  const unsigned short* hb = Asrc + (long)node0 * 128;
  v8s v[KC];
#pragma unroll
  for (int i = 0; i < KC; ++i) {
    const int u = i * 256 + tid;
    const int r = u >> 4;
    v[i] = (v8s){0, 0, 0, 0, 0, 0, 0, 0};
    if (node0 + r < N) v[i] = *(const v8s*)(hb + 8 * u);
  }
#pragma unroll
  for (int i = 0; i < KC; ++i) {
    const int u = i * 256 + tid;
    *(v8s*)&a_s[u >> 4][(u & 15) * 8] = v[i];
  }
  __syncthreads();

  const int wave = tid >> 6, lane = tid & 63;
  const int quad = lane >> 4, l16 = lane & 15;
  v4f acc[4][2];
#pragma unroll
  for (int mt = 0; mt < 4; ++mt)
#pragma unroll
    for (int nt = 0; nt < 2; ++nt) acc[mt][nt] = (v4f){0.f, 0.f, 0.f, 0.f};

  const unsigned short* wb = wpk + (wave * 32 + l16) * 32 + quad * 8;
#pragma unroll
  for (int kc = 0; kc < KC; ++kc) {
    v8s wf[2];
#pragma unroll
    for (int nt = 0; nt < 2; ++nt)
      wf[nt] = *(const v8s*)(wb + kc * 4096 + nt * 512);
#pragma unroll
    for (int mt = 0; mt < 4; ++mt) {
      v8s nf = *(const v8s*)(&a_s[mt * 16 + l16][kc * 32 + quad * 8]);
#pragma unroll
      for (int nt = 0; nt < 2; ++nt)
        acc[mt][nt] = __builtin_amdgcn_mfma_f32_16x16x32_bf16(wf[nt], nf, acc[mt][nt], 0, 0, 0);
    }
  }

#pragma unroll
  for (int mt = 0; mt < 4; ++mt) {
    const int rw = node0 + mt * 16 + l16;
    if (rw < N) {
#pragma unroll
      for (int nt = 0; nt < 2; ++nt) {
        const int oc = wave * 32 + nt * 16 + quad * 4;
        v4us v;
        v[0] = f2bf(acc[mt][nt][0]);
        v[1] = f2bf(acc[mt][nt][1]);
        v[2] = f2bf(acc[mt][nt][2]);
        v[3] = f2bf(acc[mt][nt][3]);
        *(v4us*)(O + (long)rw * 128 + oc) = v;
      }
    }
  }
}

// ---------- fused aggregate + ROOT GEMM, SCALARIZED gather control path (round-7):
//   out = relu((mean(gsrc[nbr]) + rsrc_tile @ Wr) * s + t)
// 16 nodes/block, 4 nodes/wave; CSR state wave-uniform (SALU/s_load); ragged slots
// select the zeroed sentinel row N; nbr over-reads clamped to E-1.
template<int KC, bool SRCF32, bool OUTF32>
__global__ __launch_bounds__(256) void spmmR_k(const unsigned short* __restrict__ gsrc,
                                               const void* __restrict__ rsrc,
                                               const unsigned short* __restrict__ wpkr,
                                               const int* __restrict__ rowptr,
                                               const int* __restrict__ nbr,
                                               const float* __restrict__ sc,
                                               const float* __restrict__ tc,
                                               void* __restrict__ out, int N, int E) {
  constexpr int LXS = SRCF32 ? 168 : 136;
  __shared__ __align__(16) unsigned short xls[16][LXS];
  __shared__ __align__(16) float rls[16][132];
  const int tid = threadIdx.x;
  const int lane = tid & 63;
  const int wu = __builtin_amdgcn_readfirstlane(tid >> 6);
  const int quad = lane >> 4, l16 = lane & 15;
  const int nb0 = blockIdx.x * 16;

  if constexpr (SRCF32) {
    {
      if (tid < 64) {
        v8s z = {0, 0, 0, 0, 0, 0, 0, 0};
        *(v8s*)&xls[tid >> 2][136 + (tid & 3) * 8] = z;
      }
      if (tid < 48) {
        const int r3 = tid / 3, p3 = tid - 3 * r3;
        *(unsigned int*)&xls[r3][130 + 2 * p3] = 0u;
      }
    }
    const float* xb = (const float*)rsrc + (long)nb0 * 130;
    if (nb0 + 16 <= N) {
      float4 v[3];
#pragma unroll
      for (int i = 0; i < 3; ++i) {
        const int g = i * 256 + tid;
        if (g < 520) v[i] = *(const float4*)(xb + 4 * g);
      }
#pragma unroll
      for (int i = 0; i < 3; ++i) {
        const int g = i * 256 + tid;
        if (g < 520) {
          const int p0 = 2 * g, p1 = 2 * g + 1;
          const int r0_ = (p0 * 4033) >> 18, r1_ = (p1 * 4033) >> 18;
          const int c0_ = p0 - 65 * r0_, c1_ = p1 - 65 * r1_;
          *(ushort2*)&xls[r0_][2 * c0_] = pk(make_float2(v[i].x, v[i].y));
          *(ushort2*)&xls[r1_][2 * c1_] = pk(make_float2(v[i].z, v[i].w));
        }
      }
    } else {
      for (int i = 0; i < 3; ++i) {
        const int g = i * 256 + tid;
        if (g < 520) {
#pragma unroll
          for (int h = 0; h < 2; ++h) {
            const int p = 2 * g + h;
            const int r = (p * 4033) >> 18;
            const int c = p - 65 * r;
            float2 vv = make_float2(0.f, 0.f);
            if (nb0 + r < N)
              vv = *(const float2*)((const float*)rsrc + (long)(nb0 + r) * 130 + 2 * c);
            *(ushort2*)&xls[r][2 * c] = pk(vv);
          }
        }
      }
    }
  } else {
    const unsigned short* hb = (const unsigned short*)rsrc + (long)nb0 * 128;
    const int r = tid >> 4, c = (tid & 15) * 8;
    v8s v = {0, 0, 0, 0, 0, 0, 0, 0};
    if (nb0 + r < N) v = *(const v8s*)(hb + (long)r * 128 + c);
    *(v8s*)&xls[r][c] = v;
  }

  // ---- scalar CSR setup (wave-uniform) ----
  const int nb = nb0 + wu * 4;
  int r0[4], d[4];
#pragma unroll
  for (int r = 0; r < 4; ++r) {
    const int i0 = min(nb + r, N);
    const int i1 = min(nb + r + 1, N);
    r0[r] = rowptr[i0];
    const int r1 = rowptr[i1];
    d[r] = (nb + r < N) ? (r1 - r0[r]) : 0;
  }
  const int dm = max(max(d[0], d[1]), max(d[2], d[3]));
  float2 a[4];
#pragma unroll
  for (int r = 0; r < 4; ++r) a[r] = make_float2(0.f, 0.f);

  __syncthreads();   // xls ready

  // ---- root GEMM: wave wu covers feats [wu*32, wu*32+32) ----
  {
    v4f racc[2];
    racc[0] = (v4f){0.f, 0.f, 0.f, 0.f};
    racc[1] = (v4f){0.f, 0.f, 0.f, 0.f};
    const unsigned short* wb = wpkr + (wu * 32 + l16) * 32 + quad * 8;
#pragma unroll
    for (int kc = 0; kc < KC; ++kc) {
      v8s nf = *(const v8s*)&xls[l16][kc * 32 + quad * 8];
#pragma unroll
      for (int nt = 0; nt < 2; ++nt) {
        v8s wf = *(const v8s*)(wb + kc * 4096 + nt * 512);
        racc[nt] = __builtin_amdgcn_mfma_f32_16x16x32_bf16(wf, nf, racc[nt], 0, 0, 0);
      }
    }
#pragma unroll
    for (int nt = 0; nt < 2; ++nt)
      *(v4f*)&rls[l16][wu * 32 + nt * 16 + quad * 4] = racc[nt];
  }

  // ---- gather-mean: uniform chunk loop, scalar addresses ----
  const int lofs = lane << 1;
  for (int e0 = 0; e0 < dm; e0 += 8) {
    unsigned int u[4][8];
#pragma unroll
    for (int j = 0; j < 8; ++j)
#pragma unroll
      for (int r = 0; r < 4; ++r) {
        const int e = e0 + j;
        const int nv = nbr[min(r0[r] + e, E - 1)];
        const int idx = (e < d[r]) ? nv : N;
        u[r][j] = *(const unsigned int*)(gsrc + ((long)idx << 7) + lofs);
      }
#pragma unroll
    for (int r = 0; r < 4; ++r)
#pragma unroll
      for (int j = 0; j < 8; ++j) {
        a[r].x += bf2f(u[r][j] & 0xffffu);
        a[r].y += bf2f(u[r][j] >> 16);
      }
  }

  __syncthreads();   // rls ready

  const float2 sv = *(const float2*)(sc + 2 * lane);
  const float2 tv = *(const float2*)(tc + 2 * lane);
#pragma unroll
  for (int r = 0; r < 4; ++r) {
    if (nb + r < N) {
      const float inv = 1.0f / fmaxf((float)d[r], 1.0f);
      const float2 rt = *(const float2*)&rls[wu * 4 + r][2 * lane];
      float yx = a[r].x * inv + rt.x;
      float yy = a[r].y * inv + rt.y;
      yx = fmaxf(yx * sv.x + tv.x, 0.f);
      yy = fmaxf(yy * sv.y + tv.y, 0.f);
      if (OUTF32) {
        *(float2*)((float*)out + (long)(nb + r) * 128 + 2 * lane) = make_float2(yx, yy);
      } else {
        *(ushort2*)((unsigned short*)out + (long)(nb + r) * 128 + 2 * lane) =
            pk(make_float2(yx, yy));
      }
    }
  }
}

extern "C" void kernel_launch(void* const* d_in, const int* in_sizes, int n_in,
                              void* d_out, int out_size, void* d_ws, size_t ws_size,
                              hipStream_t stream) {
  const float* x   = (const float*)d_in[0];
  const int*   ei  = (const int*)d_in[1];
  const float* W1l = (const float*)d_in[2];
  const float* b1  = (const float*)d_in[3];
  const float* W1r = (const float*)d_in[4];
  const float* g1  = (const float*)d_in[5];
  const float* be1 = (const float*)d_in[6];
  const float* rm1 = (const float*)d_in[7];
  const float* rv1 = (const float*)d_in[8];
  const float* W2l = (const float*)d_in[9];
  const float* b2  = (const float*)d_in[10];
  const float* W2r = (const float*)d_in[11];
  const float* g2  = (const float*)d_in[12];
  const float* be2 = (const float*)d_in[13];
  const float* rm2 = (const float*)d_in[14];
  const float* rv2 = (const float*)d_in[15];

  const int E = in_sizes[1] / 2;
  const int N = in_sizes[0] / 130;
  const int* src = ei;
  const int* dst = ei + E;

  // workspace carve (~102 MB), identical to round 7
  unsigned short* bufA = (unsigned short*)d_ws;            // P1l -> P2l (gather targets)
  unsigned short* bufB = bufA + (size_t)(N + 1) * 128;     // h1
  unsigned short* wp1l = bufB + (size_t)(N + 1) * 128;     // 5*4096
  unsigned short* wp1r = wp1l + 5 * 4096;                  // 5*4096
  unsigned short* wp2l = wp1r + 5 * 4096;                  // 4*4096
  unsigned short* wp2r = wp2l + 4 * 4096;                  // 4*4096
  float* s1 = (float*)(wp2r + 4 * 4096);
  float* t1 = s1 + 128;
  float* s2 = t1 + 128;
  float* t2 = s2 + 128;
  int* degi   = (int*)(t2 + 128);   // N (reused as cursor)
  int* rowptr = degi + N;           // N+1
  int* bsum   = rowptr + N + 1;     // 256
  int* nbr    = bsum + 256;         // E

  const int NZB = (N + 255) / 256;
  const int ngb = (N + 63) / 64;
  const int ecb = (E + 255) / 256;
  const int nsb = (N + 15) / 16;

  // 1) setup: zero degi + 4 packs + bn_fold + sentinel (one dispatch)
  hipLaunchKernelGGL(setup_k, dim3(NZB + 288 + 1), dim3(256), 0, stream,
                     g1, be1, rm1, rv1, b1, g2, be2, rm2, rv2, b2,
                     W1l, W1r, W2l, W2r, s1, t1, s2, t2,
                     wp1l, wp1r, wp2l, wp2r, bufA, degi, N, NZB);

  // 2) fused: P1l = x @ W1l  ||  edge count into degi
  hipLaunchKernelGGL(gemmc_k, dim3(ngb + ecb), dim3(256), 0, stream,
                     x, wp1l, bufA, dst, degi, N, E, ngb);

  // 3) CSR scan + fill
  const int nb = (N + 1023) / 1024;
  hipLaunchKernelGGL(scan1_k, dim3(nb), dim3(256), 0, stream, degi, rowptr, bsum, N);
  hipLaunchKernelGGL(scan2_k, dim3(1), dim3(256), 0, stream, bsum, nb);
  hipLaunchKernelGGL(scan3_k, dim3((N + 256) / 256), dim3(256), 0, stream,
                     rowptr, degi, bsum, N, E);
  hipLaunchKernelGGL(fill_k, dim3(ecb), dim3(256), 0, stream,
                     src, dst, degi, nbr, E);

  // 4) layer 1 aggregate+root: h1 = relu((mean(P1l[nbr]) + x@W1r)*s1 + t1')
  hipLaunchKernelGGL((spmmR_k<5, true, false>), dim3(nsb), dim3(256), 0, stream,
                     bufA, (const void*)x, wp1r, rowptr, nbr, s1, t1, (void*)bufB, N, E);
  // 5) layer 2 dense: P2l = h1 @ W2l
  hipLaunchKernelGGL((gemmB_k<4>), dim3(ngb), dim3(256), 0, stream,
                     bufB, wp2l, bufA, N);
  // 6) layer 2 aggregate+root: out = relu((mean(P2l[nbr]) + h1@W2r)*s2 + t2')
  hipLaunchKernelGGL((spmmR_k<4, false, true>), dim3(nsb), dim3(256), 0, stream,
                     bufA, (const void*)bufB, wp2r, rowptr, nbr, s2, t2, d_out, N, E);
}